// Round 3
// baseline (510.512 us; speedup 1.0000x reference)
//
#include <hip/hip_runtime.h>
#include <hip/hip_bf16.h>

#define B_N 8192
#define C_DIM 512

typedef __attribute__((ext_vector_type(4))) float f32x4;
typedef __attribute__((ext_vector_type(8))) __bf16 bf16x8;

__device__ __forceinline__ unsigned short f2bf(float f) {
    unsigned int u = __float_as_uint(f);
    u += 0x7FFFu + ((u >> 16) & 1u);          // RNE
    return (unsigned short)(u >> 16);
}
__device__ __forceinline__ float bf2f(unsigned int s) {
    return __uint_as_float(s << 16);
}
// order-preserving key: float order -> unsigned ascending. 0 unused by real values.
__device__ __forceinline__ unsigned negkey(unsigned ub) {
    return (ub & 0x8000u) ? ((~ub) & 0xFFFFu) : (ub | 0x8000u);
}
__device__ __forceinline__ unsigned unkey(unsigned k) {
    return (k & 0x8000u) ? (k ^ 0x8000u) : ((~k) & 0xFFFFu);
}

// ---- detect int64-vs-int32 target layout, emit class bytes ----
__global__ void prep_tgt(const unsigned int* __restrict__ t, unsigned char* __restrict__ tgb) {
    __shared__ int bad;
    if (threadIdx.x == 0) bad = 0;
    __syncthreads();
    int local = 0;
    for (int k = (int)threadIdx.x; k < 4096; k += 256)   // first 32KB only: safe for both layouts
        if (t[2 * k + 1] != 0u) local = 1;
    if (local) atomicOr(&bad, 1);
    __syncthreads();
    const int is64 = (bad == 0);
    for (int j = (int)threadIdx.x; j < B_N; j += 256)
        tgb[j] = (unsigned char)(is64 ? t[2 * j] : t[j]);
}

// ---- per-class membership bitmasks: cm[c][w] bit e = (tgb[w*64+e]==c) ----
__global__ void class_masks(const unsigned char* __restrict__ tgb,
                            unsigned long long* __restrict__ cm) {
    const int c = blockIdx.x;
    const int w = threadIdx.x;          // 0..127
    const unsigned char* base = tgb + w * 64;
    unsigned long long b = 0;
    for (int e = 0; e < 64; ++e)
        b |= ((unsigned long long)(base[e] == c)) << e;
    cm[c * 128 + w] = b;
}

// ---- L2 normalize rows, emit bf16 ----
__global__ __launch_bounds__(256) void normalize_k(const float* __restrict__ x,
                                                   unsigned short* __restrict__ nf) {
    const int wid = threadIdx.x >> 6, lane = threadIdx.x & 63;
    const size_t row = (size_t)blockIdx.x * 4 + wid;
    const float4* xr = (const float4*)(x + row * C_DIM) + lane * 2;
    float4 a = xr[0], b = xr[1];
    float ss = a.x * a.x + a.y * a.y + a.z * a.z + a.w * a.w +
               b.x * b.x + b.y * b.y + b.z * b.z + b.w * b.w;
#pragma unroll
    for (int m = 1; m < 64; m <<= 1) ss += __shfl_xor(ss, m);
    float sc = 1.0f / fmaxf(sqrtf(ss), 1e-12f);
    union { unsigned short s[8]; int4 v; } o;
    o.s[0] = f2bf(a.x * sc); o.s[1] = f2bf(a.y * sc);
    o.s[2] = f2bf(a.z * sc); o.s[3] = f2bf(a.w * sc);
    o.s[4] = f2bf(b.x * sc); o.s[5] = f2bf(b.y * sc);
    o.s[6] = f2bf(b.z * sc); o.s[7] = f2bf(b.w * sc);
    *(int4*)(nf + row * C_DIM + lane * 8) = o.v;
}

// ---- sim keys = negkey(bf16(nf @ nf^T)) (bf16 MFMA, 128x128 tile) ----
__global__ __launch_bounds__(256) void gemm_sim(const unsigned short* __restrict__ nf,
                                                unsigned short* __restrict__ simk,
                                                int rowBase) {
    __shared__ unsigned short As[128][72];
    __shared__ unsigned short Bs[128][72];
    const int tid = threadIdx.x;
    const int wid = tid >> 6, lane = tid & 63;
    const int wm = wid >> 1, wn = wid & 1;
    const int gr = rowBase + blockIdx.y * 128;
    const int gc = blockIdx.x * 128;
    f32x4 zero = {0.f, 0.f, 0.f, 0.f};
    f32x4 acc[4][4];
#pragma unroll
    for (int m = 0; m < 4; ++m)
#pragma unroll
        for (int n = 0; n < 4; ++n) acc[m][n] = zero;

    for (int k0 = 0; k0 < C_DIM; k0 += 64) {
#pragma unroll
        for (int q = 0; q < 4; ++q) {
            int idx = q * 256 + tid;
            int r = idx >> 3, c = (idx & 7) << 3;
            *(int4*)&As[r][c] = *(const int4*)(nf + (size_t)(gr + r) * C_DIM + k0 + c);
            *(int4*)&Bs[r][c] = *(const int4*)(nf + (size_t)(gc + r) * C_DIM + k0 + c);
        }
        __syncthreads();
#pragma unroll
        for (int kk = 0; kk < 2; ++kk) {
            const int krow = kk * 32 + (lane >> 4) * 8;
            bf16x8 a[4], b[4];
#pragma unroll
            for (int m = 0; m < 4; ++m)
                a[m] = *(const bf16x8*)&As[wm * 64 + m * 16 + (lane & 15)][krow];
#pragma unroll
            for (int n = 0; n < 4; ++n)
                b[n] = *(const bf16x8*)&Bs[wn * 64 + n * 16 + (lane & 15)][krow];
#pragma unroll
            for (int m = 0; m < 4; ++m)
#pragma unroll
                for (int n = 0; n < 4; ++n)
                    acc[m][n] = __builtin_amdgcn_mfma_f32_16x16x32_bf16(a[m], b[n], acc[m][n], 0, 0, 0);
        }
        __syncthreads();
    }
    const int lrowBase = blockIdx.y * 128 + wm * 64;
#pragma unroll
    for (int m = 0; m < 4; ++m) {
        int r0 = lrowBase + m * 16 + ((lane >> 4) << 2);
#pragma unroll
        for (int n = 0; n < 4; ++n) {
            int col = gc + wn * 64 + n * 16 + (lane & 15);
#pragma unroll
            for (int j = 0; j < 4; ++j)
                simk[(size_t)(r0 + j) * B_N + col] =
                    (unsigned short)negkey(f2bf(acc[m][n][j]));
        }
    }
}

// all-lane wave digit select over per-wave 256-bin hist; returns digit & new krem
__device__ __forceinline__ void wave_digit(const int* __restrict__ h, int lane, int krem,
                                           int& digit, int& krem_out) {
    int a0 = h[lane * 4 + 0], a1 = h[lane * 4 + 1], a2 = h[lane * 4 + 2], a3 = h[lane * 4 + 3];
    int ls3 = a3, ls2 = a2 + ls3, ls1 = a1 + ls2, ls0 = a0 + ls1;
    int s = ls0;
#pragma unroll
    for (int off = 1; off < 64; off <<= 1) {
        int t = __shfl_down(s, off);
        if (lane + off < 64) s += t;
    }
    const int E = s - ls0;                        // suffix sum over higher lanes
    unsigned long long m = __ballot((E + ls0) >= krem);
    int hi = m ? (63 - __clzll(m)) : 0;
    int k, kr;
    if ((E + ls3) >= krem)      { k = 3; kr = krem - E; }
    else if ((E + ls2) >= krem) { k = 2; kr = krem - (E + ls3); }
    else if ((E + ls1) >= krem) { k = 1; kr = krem - (E + ls2); }
    else                        { k = 0; kr = krem - (E + ls1); }
    digit = __shfl(lane * 4 + k, hi);
    krem_out = __shfl(kr, hi);
}

// ---- wave-per-row selection + loss: NO __syncthreads anywhere ----
// lane owns elems j = q*512 + lane*8 + e  (q=0..15, e=0..7), keys in registers.
__global__ __launch_bounds__(256) void select_loss(const unsigned short* __restrict__ simk,
                                                   const unsigned char* __restrict__ tgb,
                                                   const unsigned char* __restrict__ cmb,
                                                   float* __restrict__ out, int rowBase) {
    __shared__ int hist[4][256];
    __shared__ float posbuf[4][12];
    __shared__ int posn[4];

    const int tid = threadIdx.x;
    const int wid = tid >> 6, lane = tid & 63;
    const int lrow = blockIdx.x * 4 + wid;
    const int row = rowBase + lrow;
    const unsigned int* srow = (const unsigned int*)(simk + (size_t)lrow * B_N);
    const int ti = tgb[row];
    const unsigned char* mrow = cmb + (size_t)ti * 1024;
    if (lane == 0) posn[wid] = 0;

    int4 A[16];
    unsigned mpk[4] = {0, 0, 0, 0};
#pragma unroll
    for (int q = 0; q < 16; ++q) {
        A[q] = *(const int4*)(srow + q * 256 + lane * 4);
        unsigned mb = mrow[q * 64 + lane];
        mpk[q >> 2] |= mb << (8 * (q & 3));
    }

#define ELEM_LOOP(BODY)                                                          \
    _Pragma("unroll")                                                            \
    for (int q = 0; q < 16; ++q) {                                               \
        _Pragma("unroll")                                                        \
        for (int d = 0; d < 4; ++d) {                                            \
            unsigned w32 = (unsigned)(d == 0 ? A[q].x : d == 1 ? A[q].y          \
                                    : d == 2 ? A[q].z : A[q].w);                 \
            _Pragma("unroll")                                                    \
            for (int h2 = 0; h2 < 2; ++h2) {                                     \
                unsigned key = h2 ? (w32 >> 16) : (w32 & 0xFFFFu);               \
                bool same = (mpk[q >> 2] >> (8 * (q & 3) + d * 2 + h2)) & 1u;    \
                BODY                                                             \
            }                                                                    \
        }                                                                        \
    }

    int4 z4 = {0, 0, 0, 0};
    int digit, krem;

    // ---------------- negatives: top-64 ----------------
    *(int4*)&hist[wid][lane * 4] = z4;
    ELEM_LOOP( if (!same) atomicAdd(&hist[wid][key >> 8], 1); )
    wave_digit(hist[wid], lane, 64, digit, krem);
    const unsigned nhi = (unsigned)digit;

    *(int4*)&hist[wid][lane * 4] = z4;
    ELEM_LOOP( if (!same && (key >> 8) == nhi) atomicAdd(&hist[wid][key & 0xFFu], 1); )
    wave_digit(hist[wid], lane, krem, digit, krem);
    const unsigned nprefix = (nhi << 8) | (unsigned)digit;
    const int nkrem = krem;

    // ---------------- positives: bottom-8 (flipped keys) ----------------
    *(int4*)&hist[wid][lane * 4] = z4;
    ELEM_LOOP( if (same) atomicAdd(&hist[wid][(key ^ 0xFFFFu) >> 8], 1); )
    wave_digit(hist[wid], lane, 8, digit, krem);
    const unsigned phi = (unsigned)digit;

    *(int4*)&hist[wid][lane * 4] = z4;
    ELEM_LOOP( if (same && ((key ^ 0xFFFFu) >> 8) == phi)
                   atomicAdd(&hist[wid][(key ^ 0xFFFFu) & 0xFFu], 1); )
    wave_digit(hist[wid], lane, krem, digit, krem);
    const unsigned pprefix = (phi << 8) | (unsigned)digit;
    const int pkrem = krem;

    // ---------------- final pass ----------------
    float Sl = 0.f;
    ELEM_LOOP(
        if (!same && key > nprefix) Sl += __expf(2.0f * bf2f(unkey(key)));
        if (same && (key ^ 0xFFFFu) > pprefix) {
            int p = atomicAdd(&posn[wid], 1);
            if (p < 12) posbuf[wid][p] = bf2f(unkey(key));
        }
    )
#undef ELEM_LOOP

#pragma unroll
    for (int off = 1; off < 64; off <<= 1) Sl += __shfl_xor(Sl, off);

    if (lane == 0) {
        float S = Sl;
        if (nprefix != 0u) S += (float)nkrem * __expf(2.0f * bf2f(unkey(nprefix)));
        float acc = 0.f;
        int c0 = posn[wid] < 8 ? posn[wid] : 8;
        for (int i = 0; i < c0; ++i) {
            float p = posbuf[wid][i];
            acc += logf(__expf(2.0f * p) + S) - 2.0f * p;
        }
        if (pprefix != 0u) {
            float p = bf2f(unkey(pprefix ^ 0xFFFFu));
            acc += (float)pkrem * (logf(__expf(2.0f * p) + S) - 2.0f * p);
        }
        out[row] = acc * 0.125f;
    }
}

extern "C" void kernel_launch(void* const* d_in, const int* in_sizes, int n_in,
                              void* d_out, int out_size, void* d_ws, size_t ws_size,
                              hipStream_t stream) {
    const float* newf = (const float*)d_in[1];
    const unsigned int* tgtw = (const unsigned int*)d_in[2];
    float* out = (float*)d_out;
    char* ws = (char*)d_ws;
    unsigned char* tgb = (unsigned char*)ws;                         // 8 KB
    unsigned long long* cm = (unsigned long long*)(ws + 8192);       // 100*128*8 = 100 KB
    unsigned short* nf = (unsigned short*)(ws + 110592);             // 8 MB
    unsigned short* simk = (unsigned short*)(ws + 110592 + (size_t)B_N * C_DIM * 2);

    size_t fixed = 110592 + (size_t)B_N * C_DIM * 2;
    size_t avail = (ws_size > fixed) ? (ws_size - fixed) : 0;
    long maxRows = (long)(avail / ((size_t)B_N * 2));
    int chunk = (int)((maxRows / 128) * 128);
    if (chunk < 128) chunk = 128;
    if (chunk > B_N) chunk = B_N;

    hipLaunchKernelGGL(prep_tgt, dim3(1), dim3(256), 0, stream, tgtw, tgb);
    hipLaunchKernelGGL(class_masks, dim3(100), dim3(128), 0, stream, tgb, cm);
    hipLaunchKernelGGL(normalize_k, dim3(B_N / 4), dim3(256), 0, stream, newf, nf);
    for (int r0 = 0; r0 < B_N; r0 += chunk) {
        int rows = (B_N - r0 < chunk) ? (B_N - r0) : chunk;
        hipLaunchKernelGGL(gemm_sim, dim3(64, rows / 128), dim3(256), 0, stream, nf, simk, r0);
        hipLaunchKernelGGL(select_loss, dim3(rows / 4), dim3(256), 0, stream,
                           simk, tgb, (const unsigned char*)cm, out, r0);
    }
}

// Round 4
// 226.066 us; speedup vs baseline: 2.2582x; 2.2582x over previous
//
#include <hip/hip_runtime.h>
#include <hip/hip_bf16.h>

#define B_N 8192
#define C_DIM 512

typedef __attribute__((ext_vector_type(4))) float f32x4;
typedef __attribute__((ext_vector_type(8))) __bf16 bf16x8;

__device__ __forceinline__ unsigned short f2bf(float f) {
    unsigned int u = __float_as_uint(f);
    u += 0x7FFFu + ((u >> 16) & 1u);          // RNE
    return (unsigned short)(u >> 16);
}
__device__ __forceinline__ float bf2f(unsigned int s) {
    return __uint_as_float(s << 16);
}
// order-preserving key: float order -> unsigned ascending. key 0 impossible for finite sims.
__device__ __forceinline__ unsigned negkey(unsigned ub) {
    return (ub & 0x8000u) ? ((~ub) & 0xFFFFu) : (ub | 0x8000u);
}
__device__ __forceinline__ unsigned unkey(unsigned k) {
    return (k & 0x8000u) ? (k ^ 0x8000u) : ((~k) & 0xFFFFu);
}

// ---- detect int64-vs-int32 target layout, emit class bytes ----
__global__ void prep_tgt(const unsigned int* __restrict__ t, unsigned char* __restrict__ tgb) {
    __shared__ int bad;
    if (threadIdx.x == 0) bad = 0;
    __syncthreads();
    int local = 0;
    for (int k = (int)threadIdx.x; k < 4096; k += 256)   // first 32KB only: safe for both layouts
        if (t[2 * k + 1] != 0u) local = 1;
    if (local) atomicOr(&bad, 1);
    __syncthreads();
    const int is64 = (bad == 0);
    for (int j = (int)threadIdx.x; j < B_N; j += 256)
        tgb[j] = (unsigned char)(is64 ? t[2 * j] : t[j]);
}

// ---- per-class membership bitmasks: cm[c][w] bit e = (tgb[w*64+e]==c) ----
__global__ void class_masks(const unsigned char* __restrict__ tgb,
                            unsigned long long* __restrict__ cm) {
    const int c = blockIdx.x;
    const int w = threadIdx.x;          // 0..127
    const unsigned char* base = tgb + w * 64;
    unsigned long long b = 0;
    for (int e = 0; e < 64; ++e)
        b |= ((unsigned long long)(base[e] == c)) << e;
    cm[c * 128 + w] = b;
}

// ---- L2 normalize rows, emit bf16 ----
__global__ __launch_bounds__(256) void normalize_k(const float* __restrict__ x,
                                                   unsigned short* __restrict__ nf) {
    const int wid = threadIdx.x >> 6, lane = threadIdx.x & 63;
    const size_t row = (size_t)blockIdx.x * 4 + wid;
    const float4* xr = (const float4*)(x + row * C_DIM) + lane * 2;
    float4 a = xr[0], b = xr[1];
    float ss = a.x * a.x + a.y * a.y + a.z * a.z + a.w * a.w +
               b.x * b.x + b.y * b.y + b.z * b.z + b.w * b.w;
#pragma unroll
    for (int m = 1; m < 64; m <<= 1) ss += __shfl_xor(ss, m);
    float sc = 1.0f / fmaxf(sqrtf(ss), 1e-12f);
    union { unsigned short s[8]; int4 v; } o;
    o.s[0] = f2bf(a.x * sc); o.s[1] = f2bf(a.y * sc);
    o.s[2] = f2bf(a.z * sc); o.s[3] = f2bf(a.w * sc);
    o.s[4] = f2bf(b.x * sc); o.s[5] = f2bf(b.y * sc);
    o.s[6] = f2bf(b.z * sc); o.s[7] = f2bf(b.w * sc);
    *(int4*)(nf + row * C_DIM + lane * 8) = o.v;
}

// ---- sim keys = negkey(bf16(nf @ nf^T)) (bf16 MFMA, 128x128 tile) ----
__global__ __launch_bounds__(256) void gemm_sim(const unsigned short* __restrict__ nf,
                                                unsigned short* __restrict__ simk,
                                                int rowBase) {
    __shared__ unsigned short As[128][72];
    __shared__ unsigned short Bs[128][72];
    const int tid = threadIdx.x;
    const int wid = tid >> 6, lane = tid & 63;
    const int wm = wid >> 1, wn = wid & 1;
    const int gr = rowBase + blockIdx.y * 128;
    const int gc = blockIdx.x * 128;
    f32x4 zero = {0.f, 0.f, 0.f, 0.f};
    f32x4 acc[4][4];
#pragma unroll
    for (int m = 0; m < 4; ++m)
#pragma unroll
        for (int n = 0; n < 4; ++n) acc[m][n] = zero;

    for (int k0 = 0; k0 < C_DIM; k0 += 64) {
#pragma unroll
        for (int q = 0; q < 4; ++q) {
            int idx = q * 256 + tid;
            int r = idx >> 3, c = (idx & 7) << 3;
            *(int4*)&As[r][c] = *(const int4*)(nf + (size_t)(gr + r) * C_DIM + k0 + c);
            *(int4*)&Bs[r][c] = *(const int4*)(nf + (size_t)(gc + r) * C_DIM + k0 + c);
        }
        __syncthreads();
#pragma unroll
        for (int kk = 0; kk < 2; ++kk) {
            const int krow = kk * 32 + (lane >> 4) * 8;
            bf16x8 a[4], b[4];
#pragma unroll
            for (int m = 0; m < 4; ++m)
                a[m] = *(const bf16x8*)&As[wm * 64 + m * 16 + (lane & 15)][krow];
#pragma unroll
            for (int n = 0; n < 4; ++n)
                b[n] = *(const bf16x8*)&Bs[wn * 64 + n * 16 + (lane & 15)][krow];
#pragma unroll
            for (int m = 0; m < 4; ++m)
#pragma unroll
                for (int n = 0; n < 4; ++n)
                    acc[m][n] = __builtin_amdgcn_mfma_f32_16x16x32_bf16(a[m], b[n], acc[m][n], 0, 0, 0);
        }
        __syncthreads();
    }
    const int lrowBase = blockIdx.y * 128 + wm * 64;
#pragma unroll
    for (int m = 0; m < 4; ++m) {
        int r0 = lrowBase + m * 16 + ((lane >> 4) << 2);
#pragma unroll
        for (int n = 0; n < 4; ++n) {
            int col = gc + wn * 64 + n * 16 + (lane & 15);
#pragma unroll
            for (int j = 0; j < 4; ++j)
                simk[(size_t)(r0 + j) * B_N + col] =
                    (unsigned short)negkey(f2bf(acc[m][n][j]));
        }
    }
}

// common tail of the digit select: per-lane bin counts a0..a3, suffix-scan, pick digit
__device__ __forceinline__ void digit_common(int a0, int a1, int a2, int a3, int lane,
                                             int krem, unsigned& dg, int& krem_out) {
    int ls3 = a3, ls2 = a2 + ls3, ls1 = a1 + ls2, ls0 = a0 + ls1;
    int s = ls0;
#pragma unroll
    for (int off = 1; off < 64; off <<= 1) {
        int t = __shfl_down(s, off);
        if (lane + off < 64) s += t;
    }
    const int E = s - ls0;                        // suffix sum over higher lanes
    unsigned long long m = __ballot((E + ls0) >= krem);
    int hi = m ? (63 - __clzll(m)) : 0;
    int k, kr;
    if ((E + ls3) >= krem)      { k = 3; kr = krem - E; }
    else if ((E + ls2) >= krem) { k = 2; kr = krem - (E + ls3); }
    else if ((E + ls1) >= krem) { k = 1; kr = krem - (E + ls2); }
    else                        { k = 0; kr = krem - (E + ls1); }
    dg = (unsigned)__shfl(lane * 4 + k, hi);
    krem_out = __shfl(kr, hi);
}
__device__ __forceinline__ void digit4(const int h[][256], int lane, int krem,
                                       unsigned& dg, int& krem_out) {
    int a0 = 0, a1 = 0, a2 = 0, a3 = 0;
#pragma unroll
    for (int w = 0; w < 4; ++w) {
        a0 += h[w][lane * 4 + 0]; a1 += h[w][lane * 4 + 1];
        a2 += h[w][lane * 4 + 2]; a3 += h[w][lane * 4 + 3];
    }
    digit_common(a0, a1, a2, a3, lane, krem, dg, krem_out);
}
__device__ __forceinline__ void digit1(const int* h, int lane, int krem,
                                       unsigned& dg, int& krem_out) {
    digit_common(h[lane * 4], h[lane * 4 + 1], h[lane * 4 + 2], h[lane * 4 + 3],
                 lane, krem, dg, krem_out);
}

// ---- block-per-row selection + loss: 3 scans, 4 barriers, all-wave digit select ----
// thread tid owns elems j = q*2048 + tid*8 + e  (q=0..3, e=0..7), keys in registers.
__global__ __launch_bounds__(256) void select_loss(const unsigned short* __restrict__ simk,
                                                   const unsigned char* __restrict__ tgb,
                                                   const unsigned char* __restrict__ cmb,
                                                   float* __restrict__ out, int rowBase) {
    __shared__ int hN1[4][256];
    __shared__ int hN2[4][256];
    __shared__ int hP1[256];
    __shared__ int hP2[256];
    __shared__ float s_partial[4];
    __shared__ float posbuf[12];
    __shared__ int posn;

    const int tid = threadIdx.x;
    const int wid = tid >> 6, lane = tid & 63;
    const int row = rowBase + blockIdx.x;
    const unsigned short* srow = simk + (size_t)blockIdx.x * B_N;
    const int ti = tgb[row];
    const unsigned char* mrow = cmb + (size_t)ti * 1024;

    // load 32 keys + class-mask bits into registers (coalesced)
    int4 A[4];
    unsigned mpk = 0;
#pragma unroll
    for (int q = 0; q < 4; ++q) {
        A[q] = *(const int4*)(srow + q * 2048 + tid * 8);
        mpk |= ((unsigned)mrow[q * 256 + tid]) << (8 * q);
    }

    // zero all hists once
    int4 z4 = {0, 0, 0, 0};
    ((int4*)hN1)[tid] = z4;
    ((int4*)hN2)[tid] = z4;
    hP1[tid] = 0; hP2[tid] = 0;
    if (tid == 0) posn = 0;
    __syncthreads();                                             // barrier 1

#define ELEM_LOOP(BODY)                                                          \
    _Pragma("unroll")                                                            \
    for (int q = 0; q < 4; ++q) {                                                \
        _Pragma("unroll")                                                        \
        for (int d = 0; d < 4; ++d) {                                            \
            unsigned w32 = (unsigned)(d == 0 ? A[q].x : d == 1 ? A[q].y          \
                                    : d == 2 ? A[q].z : A[q].w);                 \
            _Pragma("unroll")                                                    \
            for (int h2 = 0; h2 < 2; ++h2) {                                     \
                unsigned key = h2 ? (w32 >> 16) : (w32 & 0xFFFFu);               \
                bool same = (mpk >> (q * 8 + d * 2 + h2)) & 1u;                  \
                BODY                                                             \
            }                                                                    \
        }                                                                        \
    }

    // scan 1: high-byte hists for both sides
    ELEM_LOOP(
        if (!same) atomicAdd(&hN1[wid][key >> 8], 1);
        else       atomicAdd(&hP1[(key ^ 0xFFFFu) >> 8], 1);
    )
    __syncthreads();                                             // barrier 2
    unsigned nhi, phi; int nk1, pk1;
    digit4(hN1, lane, 64, nhi, nk1);
    digit1(hP1, lane, 8, phi, pk1);

    // scan 2: low-byte hists within the boundary high-byte bins
    ELEM_LOOP(
        if (!same) { if ((key >> 8) == nhi) atomicAdd(&hN2[wid][key & 0xFFu], 1); }
        else { unsigned pk = key ^ 0xFFFFu;
               if ((pk >> 8) == phi) atomicAdd(&hP2[pk & 0xFFu], 1); }
    )
    __syncthreads();                                             // barrier 3
    unsigned nlo, plo; int nkrem, pkrem;
    digit4(hN2, lane, nk1, nlo, nkrem);
    digit1(hP2, lane, pk1, plo, pkrem);
    const unsigned nprefix = (nhi << 8) | nlo;
    const unsigned pprefix = (phi << 8) | plo;

    // scan 3: accumulate selected negatives, collect strict positives
    float Sl = 0.f;
    ELEM_LOOP(
        if (!same) {
            if (key > nprefix) Sl += __expf(2.0f * bf2f(unkey(key)));
        } else {
            unsigned pk = key ^ 0xFFFFu;
            if (pk > pprefix) {
                int p = atomicAdd(&posn, 1);
                if (p < 12) posbuf[p] = bf2f(unkey(key));        // provably <= 7 entries
            }
        }
    )
#undef ELEM_LOOP
#pragma unroll
    for (int off = 1; off < 64; off <<= 1) Sl += __shfl_xor(Sl, off);
    if (lane == 0) s_partial[wid] = Sl;
    __syncthreads();                                             // barrier 4

    if (tid == 0) {
        float S = s_partial[0] + s_partial[1] + s_partial[2] + s_partial[3];
        if (nprefix != 0u) S += (float)nkrem * __expf(2.0f * bf2f(unkey(nprefix)));
        float acc = 0.f;
        int c0 = posn < 8 ? posn : 8;
        for (int i = 0; i < c0; ++i) {
            float p = posbuf[i];
            acc += logf(__expf(2.0f * p) + S) - 2.0f * p;
        }
        if (pprefix != 0u) {
            float p = bf2f(unkey(pprefix ^ 0xFFFFu));
            acc += (float)pkrem * (logf(__expf(2.0f * p) + S) - 2.0f * p);
        }
        out[row] = acc * 0.125f;
    }
}

extern "C" void kernel_launch(void* const* d_in, const int* in_sizes, int n_in,
                              void* d_out, int out_size, void* d_ws, size_t ws_size,
                              hipStream_t stream) {
    const float* newf = (const float*)d_in[1];
    const unsigned int* tgtw = (const unsigned int*)d_in[2];
    float* out = (float*)d_out;
    char* ws = (char*)d_ws;
    unsigned char* tgb = (unsigned char*)ws;                         // 8 KB
    unsigned long long* cm = (unsigned long long*)(ws + 8192);       // 100*128*8 = 100 KB
    unsigned short* nf = (unsigned short*)(ws + 110592);             // 8 MB
    unsigned short* simk = (unsigned short*)(ws + 110592 + (size_t)B_N * C_DIM * 2);

    size_t fixed = 110592 + (size_t)B_N * C_DIM * 2;
    size_t avail = (ws_size > fixed) ? (ws_size - fixed) : 0;
    long maxRows = (long)(avail / ((size_t)B_N * 2));
    int chunk = (int)((maxRows / 128) * 128);
    if (chunk < 128) chunk = 128;
    if (chunk > B_N) chunk = B_N;

    hipLaunchKernelGGL(prep_tgt, dim3(1), dim3(256), 0, stream, tgtw, tgb);
    hipLaunchKernelGGL(class_masks, dim3(100), dim3(128), 0, stream, tgb, cm);
    hipLaunchKernelGGL(normalize_k, dim3(B_N / 4), dim3(256), 0, stream, newf, nf);
    for (int r0 = 0; r0 < B_N; r0 += chunk) {
        int rows = (B_N - r0 < chunk) ? (B_N - r0) : chunk;
        hipLaunchKernelGGL(gemm_sim, dim3(64, rows / 128), dim3(256), 0, stream, nf, simk, r0);
        hipLaunchKernelGGL(select_loss, dim3(rows), dim3(256), 0, stream,
                           simk, tgb, (const unsigned char*)cm, out, r0);
    }
}

// Round 5
// 208.885 us; speedup vs baseline: 2.4440x; 1.0822x over previous
//
#include <hip/hip_runtime.h>
#include <hip/hip_bf16.h>

#define B_N 8192
#define C_DIM 512

typedef __attribute__((ext_vector_type(4))) float f32x4;
typedef __attribute__((ext_vector_type(8))) __bf16 bf16x8;

__device__ __forceinline__ unsigned short f2bf(float f) {
    unsigned int u = __float_as_uint(f);
    u += 0x7FFFu + ((u >> 16) & 1u);          // RNE
    return (unsigned short)(u >> 16);
}
__device__ __forceinline__ float bf2f(unsigned int s) {
    return __uint_as_float(s << 16);
}
// order-preserving key: float order -> unsigned ascending. key 0 / 0xFFFF impossible for finite sims.
__device__ __forceinline__ unsigned negkey(unsigned ub) {
    return (ub & 0x8000u) ? ((~ub) & 0xFFFFu) : (ub | 0x8000u);
}
__device__ __forceinline__ unsigned unkey(unsigned k) {
    return (k & 0x8000u) ? (k ^ 0x8000u) : ((~k) & 0xFFFFu);
}

// ---- detect int64-vs-int32 target layout, emit class bytes ----
__global__ void prep_tgt(const unsigned int* __restrict__ t, unsigned char* __restrict__ tgb) {
    __shared__ int bad;
    if (threadIdx.x == 0) bad = 0;
    __syncthreads();
    int local = 0;
    for (int k = (int)threadIdx.x; k < 4096; k += 256)   // first 32KB only: safe for both layouts
        if (t[2 * k + 1] != 0u) local = 1;
    if (local) atomicOr(&bad, 1);
    __syncthreads();
    const int is64 = (bad == 0);
    for (int j = (int)threadIdx.x; j < B_N; j += 256)
        tgb[j] = (unsigned char)(is64 ? t[2 * j] : t[j]);
}

// ---- per-class membership bitmasks: cm[c][w] bit e = (tgb[w*64+e]==c) ----
__global__ void class_masks(const unsigned char* __restrict__ tgb,
                            unsigned long long* __restrict__ cm) {
    const int c = blockIdx.x;
    const int w = threadIdx.x;          // 0..127
    const unsigned char* base = tgb + w * 64;
    unsigned long long b = 0;
    for (int e = 0; e < 64; ++e)
        b |= ((unsigned long long)(base[e] == c)) << e;
    cm[c * 128 + w] = b;
}

// ---- L2 normalize rows, emit bf16 ----
__global__ __launch_bounds__(256) void normalize_k(const float* __restrict__ x,
                                                   unsigned short* __restrict__ nf) {
    const int wid = threadIdx.x >> 6, lane = threadIdx.x & 63;
    const size_t row = (size_t)blockIdx.x * 4 + wid;
    const float4* xr = (const float4*)(x + row * C_DIM) + lane * 2;
    float4 a = xr[0], b = xr[1];
    float ss = a.x * a.x + a.y * a.y + a.z * a.z + a.w * a.w +
               b.x * b.x + b.y * b.y + b.z * b.z + b.w * b.w;
#pragma unroll
    for (int m = 1; m < 64; m <<= 1) ss += __shfl_xor(ss, m);
    float sc = 1.0f / fmaxf(sqrtf(ss), 1e-12f);
    union { unsigned short s[8]; int4 v; } o;
    o.s[0] = f2bf(a.x * sc); o.s[1] = f2bf(a.y * sc);
    o.s[2] = f2bf(a.z * sc); o.s[3] = f2bf(a.w * sc);
    o.s[4] = f2bf(b.x * sc); o.s[5] = f2bf(b.y * sc);
    o.s[6] = f2bf(b.z * sc); o.s[7] = f2bf(b.w * sc);
    *(int4*)(nf + row * C_DIM + lane * 8) = o.v;
}

// ---- sim keys = negkey(bf16(nf @ nf^T)) (bf16 MFMA, 128x128 tile) ----
__global__ __launch_bounds__(256) void gemm_sim(const unsigned short* __restrict__ nf,
                                                unsigned short* __restrict__ simk,
                                                int rowBase) {
    __shared__ unsigned short As[128][72];
    __shared__ unsigned short Bs[128][72];
    const int tid = threadIdx.x;
    const int wid = tid >> 6, lane = tid & 63;
    const int wm = wid >> 1, wn = wid & 1;
    const int gr = rowBase + blockIdx.y * 128;
    const int gc = blockIdx.x * 128;
    f32x4 zero = {0.f, 0.f, 0.f, 0.f};
    f32x4 acc[4][4];
#pragma unroll
    for (int m = 0; m < 4; ++m)
#pragma unroll
        for (int n = 0; n < 4; ++n) acc[m][n] = zero;

    for (int k0 = 0; k0 < C_DIM; k0 += 64) {
#pragma unroll
        for (int q = 0; q < 4; ++q) {
            int idx = q * 256 + tid;
            int r = idx >> 3, c = (idx & 7) << 3;
            *(int4*)&As[r][c] = *(const int4*)(nf + (size_t)(gr + r) * C_DIM + k0 + c);
            *(int4*)&Bs[r][c] = *(const int4*)(nf + (size_t)(gc + r) * C_DIM + k0 + c);
        }
        __syncthreads();
#pragma unroll
        for (int kk = 0; kk < 2; ++kk) {
            const int krow = kk * 32 + (lane >> 4) * 8;
            bf16x8 a[4], b[4];
#pragma unroll
            for (int m = 0; m < 4; ++m)
                a[m] = *(const bf16x8*)&As[wm * 64 + m * 16 + (lane & 15)][krow];
#pragma unroll
            for (int n = 0; n < 4; ++n)
                b[n] = *(const bf16x8*)&Bs[wn * 64 + n * 16 + (lane & 15)][krow];
#pragma unroll
            for (int m = 0; m < 4; ++m)
#pragma unroll
                for (int n = 0; n < 4; ++n)
                    acc[m][n] = __builtin_amdgcn_mfma_f32_16x16x32_bf16(a[m], b[n], acc[m][n], 0, 0, 0);
        }
        __syncthreads();
    }
    const int lrowBase = blockIdx.y * 128 + wm * 64;
#pragma unroll
    for (int m = 0; m < 4; ++m) {
        int r0 = lrowBase + m * 16 + ((lane >> 4) << 2);
#pragma unroll
        for (int n = 0; n < 4; ++n) {
            int col = gc + wn * 64 + n * 16 + (lane & 15);
#pragma unroll
            for (int j = 0; j < 4; ++j)
                simk[(size_t)(r0 + j) * B_N + col] =
                    (unsigned short)negkey(f2bf(acc[m][n][j]));
        }
    }
}

// digit select: per-lane bin counts a0..a3 of a 256-bin hist, suffix-scan, pick digit
__device__ __forceinline__ void digit_common(int a0, int a1, int a2, int a3, int lane,
                                             int krem, unsigned& dg, int& krem_out) {
    int ls3 = a3, ls2 = a2 + ls3, ls1 = a1 + ls2, ls0 = a0 + ls1;
    int s = ls0;
#pragma unroll
    for (int off = 1; off < 64; off <<= 1) {
        int t = __shfl_down(s, off);
        if (lane + off < 64) s += t;
    }
    const int E = s - ls0;                        // suffix sum over higher lanes
    unsigned long long m = __ballot((E + ls0) >= krem);
    int hi = m ? (63 - __clzll(m)) : 0;
    int k, kr;
    if ((E + ls3) >= krem)      { k = 3; kr = krem - E; }
    else if ((E + ls2) >= krem) { k = 2; kr = krem - (E + ls3); }
    else if ((E + ls1) >= krem) { k = 1; kr = krem - (E + ls2); }
    else                        { k = 0; kr = krem - (E + ls1); }
    dg = (unsigned)__shfl(lane * 4 + k, hi);
    krem_out = __shfl(kr, hi);
}
__device__ __forceinline__ void digit4(const int h[][256], int lane, int krem,
                                       unsigned& dg, int& krem_out) {
    int a0 = 0, a1 = 0, a2 = 0, a3 = 0;
#pragma unroll
    for (int w = 0; w < 4; ++w) {
        a0 += h[w][lane * 4 + 0]; a1 += h[w][lane * 4 + 1];
        a2 += h[w][lane * 4 + 2]; a3 += h[w][lane * 4 + 3];
    }
    digit_common(a0, a1, a2, a3, lane, krem, dg, krem_out);
}
__device__ __forceinline__ void digit1(const int* h, int lane, int krem,
                                       unsigned& dg, int& krem_out) {
    digit_common(h[lane * 4], h[lane * 4 + 1], h[lane * 4 + 2], h[lane * 4 + 3],
                 lane, krem, dg, krem_out);
}

// ---- block-per-row selection + loss ----
// 16 lane-group split hists (stride 257: group g, bin b -> bank (g+b)%32) kill the
// same-address atomic serialization measured as SQ_LDS_BANK_CONFLICT=1.97e7.
// Positives are compact-collected (~82 of 8192) and solved by wave-0 shfl-argmin.
__global__ __launch_bounds__(256) void select_loss(const unsigned short* __restrict__ simk,
                                                   const unsigned char* __restrict__ tgb,
                                                   const unsigned char* __restrict__ cmb,
                                                   float* __restrict__ out, int rowBase) {
    __shared__ int hG[16 * 257];       // 16.4 KB: lane-group hists, padded stride
    __shared__ int hN2[4][256];        // per-wave low-byte hists (uniform spread)
    __shared__ int cN[256];            // compacted high-byte hist
    __shared__ int posk[512];          // same-class keys (class size ~82, cap 512)
    __shared__ float s_partial[4];
    __shared__ int posn;

    const int tid = threadIdx.x;
    const int wid = tid >> 6, lane = tid & 63;
    const int row = rowBase + blockIdx.x;
    const unsigned short* srow = simk + (size_t)blockIdx.x * B_N;
    const int ti = tgb[row];
    const unsigned char* mrow = cmb + (size_t)ti * 1024;
    int* hGg = &hG[(tid >> 4) * 257];

    // load 32 keys + class-mask bits into registers (coalesced)
    int4 A[4];
    unsigned mpk = 0;
#pragma unroll
    for (int q = 0; q < 4; ++q) {
        A[q] = *(const int4*)(srow + q * 2048 + tid * 8);
        mpk |= ((unsigned)mrow[q * 256 + tid]) << (8 * q);
    }

    // zero hists
    for (int i = tid; i < 16 * 257; i += 256) hG[i] = 0;
    int4 z4 = {0, 0, 0, 0};
    ((int4*)hN2)[tid] = z4;
    if (tid == 0) posn = 0;
    __syncthreads();                                             // B1

#define ELEM_LOOP(BODY)                                                          \
    _Pragma("unroll")                                                            \
    for (int q = 0; q < 4; ++q) {                                                \
        _Pragma("unroll")                                                        \
        for (int d = 0; d < 4; ++d) {                                            \
            unsigned w32 = (unsigned)(d == 0 ? A[q].x : d == 1 ? A[q].y          \
                                    : d == 2 ? A[q].z : A[q].w);                 \
            _Pragma("unroll")                                                    \
            for (int h2 = 0; h2 < 2; ++h2) {                                     \
                unsigned key = h2 ? (w32 >> 16) : (w32 & 0xFFFFu);               \
                bool same = (mpk >> (q * 8 + d * 2 + h2)) & 1u;                  \
                BODY                                                             \
            }                                                                    \
        }                                                                        \
    }

    // scan 1: negative high-byte group-hist; positives compact-collect
    ELEM_LOOP(
        if (!same) atomicAdd(&hGg[key >> 8], 1);
        else { int p = atomicAdd(&posn, 1); if (p < 512) posk[p] = (int)key; }
    )
    __syncthreads();                                             // B2

    // compact 16 group hists -> cN (strided reads: bank (t%32 + g)%32, conflict-free)
    {
        int s = 0;
#pragma unroll
        for (int g = 0; g < 16; ++g) s += hG[g * 257 + tid];
        cN[tid] = s;
    }
    __syncthreads();                                             // B3

    unsigned nhi; int krem;
    digit1(cN, lane, 64, nhi, krem);          // all waves redundantly (broadcast reads)

    // scan 2: low-byte hist within boundary high-byte bin (low bytes ~uniform)
    ELEM_LOOP(
        if (!same && (key >> 8) == nhi) atomicAdd(&hN2[wid][key & 0xFFu], 1);
    )
    __syncthreads();                                             // B4

    unsigned nlo; int nkrem;
    digit4(hN2, lane, krem, nlo, nkrem);
    const unsigned nprefix = (nhi << 8) | nlo;

    // scan 3: sum exp over strictly-selected negatives
    float Sl = 0.f;
    ELEM_LOOP(
        if (!same && key > nprefix) Sl += __expf(2.0f * bf2f(unkey(key)));
    )
#undef ELEM_LOOP
#pragma unroll
    for (int off = 1; off < 64; off <<= 1) Sl += __shfl_xor(Sl, off);
    if (lane == 0) s_partial[wid] = Sl;
    __syncthreads();                                             // B5

    // wave 0: bottom-8 positives by 8-round argmin over posk, then the loss
    if (wid == 0) {
        const int np = posn < 512 ? posn : 512;
        unsigned k16[8];
#pragma unroll
        for (int r = 0; r < 8; ++r) {
            unsigned best = 0xFFFFFFFFu;
            for (int j = lane; j < np; j += 64) {
                unsigned cand = (((unsigned)posk[j]) << 16) | (unsigned)j;
                best = best < cand ? best : cand;
            }
#pragma unroll
            for (int off = 1; off < 64; off <<= 1) {
                unsigned o = (unsigned)__shfl_xor((int)best, off);
                best = best < o ? best : o;
            }
            k16[r] = best >> 16;                        // 0xFFFF => none left
            if (lane == 0 && k16[r] != 0xFFFFu)
                posk[best & 0xFFFFu] = 0xFFFF;          // consume (sentinel max)
        }
        if (lane == 0) {
            float S = s_partial[0] + s_partial[1] + s_partial[2] + s_partial[3];
            if (nprefix != 0u) S += (float)nkrem * __expf(2.0f * bf2f(unkey(nprefix)));
            float acc = 0.f;
#pragma unroll
            for (int r = 0; r < 8; ++r) {
                if (k16[r] != 0xFFFFu) {                // <8 positives => zero contribution
                    float p = bf2f(unkey(k16[r]));
                    acc += logf(__expf(2.0f * p) + S) - 2.0f * p;
                }
            }
            out[row] = acc * 0.125f;
        }
    }
}

extern "C" void kernel_launch(void* const* d_in, const int* in_sizes, int n_in,
                              void* d_out, int out_size, void* d_ws, size_t ws_size,
                              hipStream_t stream) {
    const float* newf = (const float*)d_in[1];
    const unsigned int* tgtw = (const unsigned int*)d_in[2];
    float* out = (float*)d_out;
    char* ws = (char*)d_ws;
    unsigned char* tgb = (unsigned char*)ws;                         // 8 KB
    unsigned long long* cm = (unsigned long long*)(ws + 8192);       // 100*128*8 = 100 KB
    unsigned short* nf = (unsigned short*)(ws + 110592);             // 8 MB
    unsigned short* simk = (unsigned short*)(ws + 110592 + (size_t)B_N * C_DIM * 2);

    size_t fixed = 110592 + (size_t)B_N * C_DIM * 2;
    size_t avail = (ws_size > fixed) ? (ws_size - fixed) : 0;
    long maxRows = (long)(avail / ((size_t)B_N * 2));
    int chunk = (int)((maxRows / 128) * 128);
    if (chunk < 128) chunk = 128;
    if (chunk > B_N) chunk = B_N;

    hipLaunchKernelGGL(prep_tgt, dim3(1), dim3(256), 0, stream, tgtw, tgb);
    hipLaunchKernelGGL(class_masks, dim3(100), dim3(128), 0, stream, tgb, cm);
    hipLaunchKernelGGL(normalize_k, dim3(B_N / 4), dim3(256), 0, stream, newf, nf);
    for (int r0 = 0; r0 < B_N; r0 += chunk) {
        int rows = (B_N - r0 < chunk) ? (B_N - r0) : chunk;
        hipLaunchKernelGGL(gemm_sim, dim3(64, rows / 128), dim3(256), 0, stream, nf, simk, r0);
        hipLaunchKernelGGL(select_loss, dim3(rows), dim3(256), 0, stream,
                           simk, tgb, (const unsigned char*)cm, out, r0);
    }
}

// Round 6
// 206.114 us; speedup vs baseline: 2.4768x; 1.0134x over previous
//
#include <hip/hip_runtime.h>
#include <hip/hip_bf16.h>

#define B_N 8192
#define C_DIM 512

typedef __attribute__((ext_vector_type(4))) float f32x4;
typedef __attribute__((ext_vector_type(8))) __bf16 bf16x8;
typedef __attribute__((address_space(3))) unsigned int lds_u32;
typedef const __attribute__((address_space(1))) unsigned int glb_u32;

__device__ __forceinline__ void gl_lds16(const unsigned short* g, unsigned short* l) {
    __builtin_amdgcn_global_load_lds((glb_u32*)g, (lds_u32*)l, 16, 0, 0);
}

__device__ __forceinline__ unsigned short f2bf(float f) {
    unsigned int u = __float_as_uint(f);
    u += 0x7FFFu + ((u >> 16) & 1u);          // RNE
    return (unsigned short)(u >> 16);
}
__device__ __forceinline__ float bf2f(unsigned int s) {
    return __uint_as_float(s << 16);
}
// order-preserving key: float order -> unsigned ascending. key 0 / 0xFFFF impossible for finite sims.
__device__ __forceinline__ unsigned negkey(unsigned ub) {
    return (ub & 0x8000u) ? ((~ub) & 0xFFFFu) : (ub | 0x8000u);
}
__device__ __forceinline__ unsigned unkey(unsigned k) {
    return (k & 0x8000u) ? (k ^ 0x8000u) : ((~k) & 0xFFFFu);
}

// ---- detect int64-vs-int32 target layout, emit class bytes ----
__global__ void prep_tgt(const unsigned int* __restrict__ t, unsigned char* __restrict__ tgb) {
    __shared__ int bad;
    if (threadIdx.x == 0) bad = 0;
    __syncthreads();
    int local = 0;
    for (int k = (int)threadIdx.x; k < 4096; k += 256)   // first 32KB only: safe for both layouts
        if (t[2 * k + 1] != 0u) local = 1;
    if (local) atomicOr(&bad, 1);
    __syncthreads();
    const int is64 = (bad == 0);
    for (int j = (int)threadIdx.x; j < B_N; j += 256)
        tgb[j] = (unsigned char)(is64 ? t[2 * j] : t[j]);
}

// ---- per-class membership bitmasks: cm[c][w] bit e = (tgb[w*64+e]==c) ----
__global__ void class_masks(const unsigned char* __restrict__ tgb,
                            unsigned long long* __restrict__ cm) {
    const int c = blockIdx.x;
    const int w = threadIdx.x;          // 0..127
    const unsigned char* base = tgb + w * 64;
    unsigned long long b = 0;
    for (int e = 0; e < 64; ++e)
        b |= ((unsigned long long)(base[e] == c)) << e;
    cm[c * 128 + w] = b;
}

// ---- L2 normalize rows, emit bf16 ----
__global__ __launch_bounds__(256) void normalize_k(const float* __restrict__ x,
                                                   unsigned short* __restrict__ nf) {
    const int wid = threadIdx.x >> 6, lane = threadIdx.x & 63;
    const size_t row = (size_t)blockIdx.x * 4 + wid;
    const float4* xr = (const float4*)(x + row * C_DIM) + lane * 2;
    float4 a = xr[0], b = xr[1];
    float ss = a.x * a.x + a.y * a.y + a.z * a.z + a.w * a.w +
               b.x * b.x + b.y * b.y + b.z * b.z + b.w * b.w;
#pragma unroll
    for (int m = 1; m < 64; m <<= 1) ss += __shfl_xor(ss, m);
    float sc = 1.0f / fmaxf(sqrtf(ss), 1e-12f);
    union { unsigned short s[8]; int4 v; } o;
    o.s[0] = f2bf(a.x * sc); o.s[1] = f2bf(a.y * sc);
    o.s[2] = f2bf(a.z * sc); o.s[3] = f2bf(a.w * sc);
    o.s[4] = f2bf(b.x * sc); o.s[5] = f2bf(b.y * sc);
    o.s[6] = f2bf(b.z * sc); o.s[7] = f2bf(b.w * sc);
    *(int4*)(nf + row * C_DIM + lane * 8) = o.v;
}

// ---- sim keys = negkey(bf16(nf @ nf^T)), m97 structure: global_load_lds staging ----
__global__ __launch_bounds__(256) void gemm_sim(const unsigned short* __restrict__ nf,
                                                unsigned short* __restrict__ simk,
                                                int rowBase) {
    __shared__ unsigned short As[128 * 64];   // linear, unpadded (gl_lds requirement)
    __shared__ unsigned short Bs[128 * 64];
    const int tid = threadIdx.x;
    const int wid = tid >> 6, lane = tid & 63;
    const int wm = wid >> 1, wn = wid & 1;
    const int gr = rowBase + blockIdx.y * 128;
    const int gc = blockIdx.x * 128;
    f32x4 zero = {0.f, 0.f, 0.f, 0.f};
    f32x4 acc[4][4];
#pragma unroll
    for (int m = 0; m < 4; ++m)
#pragma unroll
        for (int n = 0; n < 4; ++n) acc[m][n] = zero;

    // per-lane source offset within a chunk: chunk = 8 rows x 64 cols; lane covers 8 shorts
    const int lr = lane >> 3, lc = (lane & 7) * 8;

    for (int k0 = 0; k0 < C_DIM; k0 += 64) {
#pragma unroll
        for (int i = 0; i < 4; ++i) {
            const int chunk = wid * 4 + i;                 // 0..15, wave-uniform
            const int r = chunk * 8 + lr;
            gl_lds16(nf + (size_t)(gr + r) * C_DIM + k0 + lc, As + chunk * 512);
            gl_lds16(nf + (size_t)(gc + r) * C_DIM + k0 + lc, Bs + chunk * 512);
        }
        __syncthreads();                                   // drains vmcnt before use
#pragma unroll
        for (int kk = 0; kk < 2; ++kk) {
            const int krow = kk * 32 + (lane >> 4) * 8;
            bf16x8 a[4], b[4];
#pragma unroll
            for (int m = 0; m < 4; ++m)
                a[m] = *(const bf16x8*)&As[(wm * 64 + m * 16 + (lane & 15)) * 64 + krow];
#pragma unroll
            for (int n = 0; n < 4; ++n)
                b[n] = *(const bf16x8*)&Bs[(wn * 64 + n * 16 + (lane & 15)) * 64 + krow];
#pragma unroll
            for (int m = 0; m < 4; ++m)
#pragma unroll
                for (int n = 0; n < 4; ++n)
                    acc[m][n] = __builtin_amdgcn_mfma_f32_16x16x32_bf16(a[m], b[n], acc[m][n], 0, 0, 0);
        }
        __syncthreads();
    }
    const int lrowBase = blockIdx.y * 128 + wm * 64;
#pragma unroll
    for (int m = 0; m < 4; ++m) {
        int r0 = lrowBase + m * 16 + ((lane >> 4) << 2);
#pragma unroll
        for (int n = 0; n < 4; ++n) {
            int col = gc + wn * 64 + n * 16 + (lane & 15);
#pragma unroll
            for (int j = 0; j < 4; ++j)
                simk[(size_t)(r0 + j) * B_N + col] =
                    (unsigned short)negkey(f2bf(acc[m][n][j]));
        }
    }
}

// digit select: per-lane bin counts a0..a3 of a 256-bin hist, suffix-scan, pick digit
__device__ __forceinline__ void digit_common(int a0, int a1, int a2, int a3, int lane,
                                             int krem, unsigned& dg, int& krem_out) {
    int ls3 = a3, ls2 = a2 + ls3, ls1 = a1 + ls2, ls0 = a0 + ls1;
    int s = ls0;
#pragma unroll
    for (int off = 1; off < 64; off <<= 1) {
        int t = __shfl_down(s, off);
        if (lane + off < 64) s += t;
    }
    const int E = s - ls0;                        // suffix sum over higher lanes
    unsigned long long m = __ballot((E + ls0) >= krem);
    int hi = m ? (63 - __clzll(m)) : 0;
    int k, kr;
    if ((E + ls3) >= krem)      { k = 3; kr = krem - E; }
    else if ((E + ls2) >= krem) { k = 2; kr = krem - (E + ls3); }
    else if ((E + ls1) >= krem) { k = 1; kr = krem - (E + ls2); }
    else                        { k = 0; kr = krem - (E + ls1); }
    dg = (unsigned)__shfl(lane * 4 + k, hi);
    krem_out = __shfl(kr, hi);
}
__device__ __forceinline__ void digit4(const int h[][256], int lane, int krem,
                                       unsigned& dg, int& krem_out) {
    int a0 = 0, a1 = 0, a2 = 0, a3 = 0;
#pragma unroll
    for (int w = 0; w < 4; ++w) {
        a0 += h[w][lane * 4 + 0]; a1 += h[w][lane * 4 + 1];
        a2 += h[w][lane * 4 + 2]; a3 += h[w][lane * 4 + 3];
    }
    digit_common(a0, a1, a2, a3, lane, krem, dg, krem_out);
}
__device__ __forceinline__ void digit1(const int* h, int lane, int krem,
                                       unsigned& dg, int& krem_out) {
    digit_common(h[lane * 4], h[lane * 4 + 1], h[lane * 4 + 2], h[lane * 4 + 3],
                 lane, krem, dg, krem_out);
}

// ---- block-per-row selection + loss ----
// scan1: 16 four-lane-group hists (stride 257 -> distinct banks): same-address
// serialization 4-way (1.58x, m136) instead of 16-way (5.7x).
// scan3: strictly-above-threshold negatives (provably <=63) compacted to a list;
// wave 0 does the few exps. Positives compact-collected, wave-0 argmin.
__global__ __launch_bounds__(256) void select_loss(const unsigned short* __restrict__ simk,
                                                   const unsigned char* __restrict__ tgb,
                                                   const unsigned char* __restrict__ cmb,
                                                   float* __restrict__ out, int rowBase) {
    __shared__ int hG[16 * 257];       // 16.4 KB lane-group hists
    __shared__ int hN2[4][256];        // per-wave low-byte hists (uniform spread)
    __shared__ int cN[256];            // compacted high-byte hist
    __shared__ int posk[512];          // same-class keys (class size ~82)
    __shared__ int nlist[64];          // strictly-selected negative keys (<=63)
    __shared__ int posn, nln;

    const int tid = threadIdx.x;
    const int wid = tid >> 6, lane = tid & 63;
    const int row = rowBase + blockIdx.x;
    const unsigned short* srow = simk + (size_t)blockIdx.x * B_N;
    const int ti = tgb[row];
    const unsigned char* mrow = cmb + (size_t)ti * 1024;
    int* hGg = &hG[((tid >> 2) & 15) * 257];

    // load 32 keys + class-mask bits into registers (coalesced)
    int4 A[4];
    unsigned mpk = 0;
#pragma unroll
    for (int q = 0; q < 4; ++q) {
        A[q] = *(const int4*)(srow + q * 2048 + tid * 8);
        mpk |= ((unsigned)mrow[q * 256 + tid]) << (8 * q);
    }

    // zero hists
    for (int i = tid; i < 16 * 257; i += 256) hG[i] = 0;
    int4 z4 = {0, 0, 0, 0};
    ((int4*)hN2)[tid] = z4;
    if (tid == 0) { posn = 0; nln = 0; }
    __syncthreads();                                             // B1

#define ELEM_LOOP(BODY)                                                          \
    _Pragma("unroll")                                                            \
    for (int q = 0; q < 4; ++q) {                                                \
        _Pragma("unroll")                                                        \
        for (int d = 0; d < 4; ++d) {                                            \
            unsigned w32 = (unsigned)(d == 0 ? A[q].x : d == 1 ? A[q].y          \
                                    : d == 2 ? A[q].z : A[q].w);                 \
            _Pragma("unroll")                                                    \
            for (int h2 = 0; h2 < 2; ++h2) {                                     \
                unsigned key = h2 ? (w32 >> 16) : (w32 & 0xFFFFu);               \
                bool same = (mpk >> (q * 8 + d * 2 + h2)) & 1u;                  \
                BODY                                                             \
            }                                                                    \
        }                                                                        \
    }

    // scan 1: negative high-byte group-hist; positives compact-collect
    ELEM_LOOP(
        if (!same) atomicAdd(&hGg[key >> 8], 1);
        else { int p = atomicAdd(&posn, 1); if (p < 512) posk[p] = (int)key; }
    )
    __syncthreads();                                             // B2

    // compact 16 group hists -> cN (bank (g+tid)%32: conflict-free)
    {
        int s = 0;
#pragma unroll
        for (int g = 0; g < 16; ++g) s += hG[g * 257 + tid];
        cN[tid] = s;
    }
    __syncthreads();                                             // B3

    unsigned nhi; int krem;
    digit1(cN, lane, 64, nhi, krem);          // all waves redundantly (broadcast reads)

    // scan 2: low-byte hist within boundary high-byte bin (low bytes ~uniform)
    ELEM_LOOP(
        if (!same && (key >> 8) == nhi) atomicAdd(&hN2[wid][key & 0xFFu], 1);
    )
    __syncthreads();                                             // B4

    unsigned nlo; int nkrem;
    digit4(hN2, lane, krem, nlo, nkrem);
    const unsigned nprefix = (nhi << 8) | nlo;

    // scan 3: compact strictly-selected negatives (count = 64 - nkrem <= 63)
    ELEM_LOOP(
        if (!same && key > nprefix) {
            int p = atomicAdd(&nln, 1);
            if (p < 64) nlist[p] = (int)key;
        }
    )
#undef ELEM_LOOP
    __syncthreads();                                             // B5

    // wave 0: exp-sum the <=63 negatives, bottom-8 positives by argmin, loss
    if (wid == 0) {
        const int ncnt = nln < 64 ? nln : 64;
        float Sl = (lane < ncnt) ? __expf(2.0f * bf2f(unkey((unsigned)nlist[lane]))) : 0.f;
#pragma unroll
        for (int off = 1; off < 64; off <<= 1) Sl += __shfl_xor(Sl, off);

        const int np = posn < 512 ? posn : 512;
        unsigned k16[8];
#pragma unroll
        for (int r = 0; r < 8; ++r) {
            unsigned best = 0xFFFFFFFFu;
            for (int j = lane; j < np; j += 64) {
                unsigned cand = (((unsigned)posk[j]) << 16) | (unsigned)j;
                best = best < cand ? best : cand;
            }
#pragma unroll
            for (int off = 1; off < 64; off <<= 1) {
                unsigned o = (unsigned)__shfl_xor((int)best, off);
                best = best < o ? best : o;
            }
            k16[r] = best >> 16;                        // 0xFFFF => none left
            if (lane == 0 && k16[r] != 0xFFFFu)
                posk[best & 0xFFFFu] = 0xFFFF;          // consume (sentinel max)
        }
        if (lane == 0) {
            float S = Sl;
            if (nprefix != 0u) S += (float)nkrem * __expf(2.0f * bf2f(unkey(nprefix)));
            float acc = 0.f;
#pragma unroll
            for (int r = 0; r < 8; ++r) {
                if (k16[r] != 0xFFFFu) {                // <8 positives => zero contribution
                    float p = bf2f(unkey(k16[r]));
                    acc += logf(__expf(2.0f * p) + S) - 2.0f * p;
                }
            }
            out[row] = acc * 0.125f;
        }
    }
}

extern "C" void kernel_launch(void* const* d_in, const int* in_sizes, int n_in,
                              void* d_out, int out_size, void* d_ws, size_t ws_size,
                              hipStream_t stream) {
    const float* newf = (const float*)d_in[1];
    const unsigned int* tgtw = (const unsigned int*)d_in[2];
    float* out = (float*)d_out;
    char* ws = (char*)d_ws;
    unsigned char* tgb = (unsigned char*)ws;                         // 8 KB
    unsigned long long* cm = (unsigned long long*)(ws + 8192);       // 100*128*8 = 100 KB
    unsigned short* nf = (unsigned short*)(ws + 110592);             // 8 MB
    unsigned short* simk = (unsigned short*)(ws + 110592 + (size_t)B_N * C_DIM * 2);

    size_t fixed = 110592 + (size_t)B_N * C_DIM * 2;
    size_t avail = (ws_size > fixed) ? (ws_size - fixed) : 0;
    long maxRows = (long)(avail / ((size_t)B_N * 2));
    int chunk = (int)((maxRows / 128) * 128);
    if (chunk < 128) chunk = 128;
    if (chunk > B_N) chunk = B_N;

    hipLaunchKernelGGL(prep_tgt, dim3(1), dim3(256), 0, stream, tgtw, tgb);
    hipLaunchKernelGGL(class_masks, dim3(100), dim3(128), 0, stream, tgb, cm);
    hipLaunchKernelGGL(normalize_k, dim3(B_N / 4), dim3(256), 0, stream, newf, nf);
    for (int r0 = 0; r0 < B_N; r0 += chunk) {
        int rows = (B_N - r0 < chunk) ? (B_N - r0) : chunk;
        hipLaunchKernelGGL(gemm_sim, dim3(64, rows / 128), dim3(256), 0, stream, nf, simk, r0);
        hipLaunchKernelGGL(select_loss, dim3(rows), dim3(256), 0, stream,
                           simk, tgb, (const unsigned char*)cm, out, r0);
    }
}

// Round 7
// 177.344 us; speedup vs baseline: 2.8787x; 1.1622x over previous
//
#include <hip/hip_runtime.h>
#include <hip/hip_bf16.h>

#define B_N 8192
#define C_DIM 512
#define NT 64    // 128-wide tiles per dimension

typedef __attribute__((ext_vector_type(4))) float f32x4;
typedef __attribute__((ext_vector_type(8))) __bf16 bf16x8;
typedef __attribute__((address_space(3))) unsigned int lds_u32;
typedef const __attribute__((address_space(1))) unsigned int glb_u32;

__device__ __forceinline__ void gl_lds16(const unsigned short* g, unsigned short* l) {
    __builtin_amdgcn_global_load_lds((glb_u32*)g, (lds_u32*)l, 16, 0, 0);
}

__device__ __forceinline__ unsigned short f2bf(float f) {
    unsigned int u = __float_as_uint(f);
    u += 0x7FFFu + ((u >> 16) & 1u);          // RNE
    return (unsigned short)(u >> 16);
}
__device__ __forceinline__ float bf2f(unsigned int s) {
    return __uint_as_float(s << 16);
}
// order-preserving key: float order -> unsigned ascending. key 0 / 0xFFFF impossible for finite sims.
__device__ __forceinline__ unsigned negkey(unsigned ub) {
    return (ub & 0x8000u) ? ((~ub) & 0xFFFFu) : (ub | 0x8000u);
}
__device__ __forceinline__ unsigned unkey(unsigned k) {
    return (k & 0x8000u) ? (k ^ 0x8000u) : ((~k) & 0xFFFFu);
}

// ---- detect int64-vs-int32 target layout, emit class bytes ----
__global__ void prep_tgt(const unsigned int* __restrict__ t, unsigned char* __restrict__ tgb) {
    __shared__ int bad;
    if (threadIdx.x == 0) bad = 0;
    __syncthreads();
    int local = 0;
    for (int k = (int)threadIdx.x; k < 4096; k += 256)   // first 32KB only: safe for both layouts
        if (t[2 * k + 1] != 0u) local = 1;
    if (local) atomicOr(&bad, 1);
    __syncthreads();
    const int is64 = (bad == 0);
    for (int j = (int)threadIdx.x; j < B_N; j += 256)
        tgb[j] = (unsigned char)(is64 ? t[2 * j] : t[j]);
}

// ---- per-class membership bitmasks: cm[c][w] bit e = (tgb[w*64+e]==c) ----
__global__ void class_masks(const unsigned char* __restrict__ tgb,
                            unsigned long long* __restrict__ cm) {
    const int c = blockIdx.x;
    const int w = threadIdx.x;          // 0..127
    const unsigned char* base = tgb + w * 64;
    unsigned long long b = 0;
    for (int e = 0; e < 64; ++e)
        b |= ((unsigned long long)(base[e] == c)) << e;
    cm[c * 128 + w] = b;
}

// ---- L2 normalize rows, emit bf16 ----
__global__ __launch_bounds__(256) void normalize_k(const float* __restrict__ x,
                                                   unsigned short* __restrict__ nf) {
    const int wid = threadIdx.x >> 6, lane = threadIdx.x & 63;
    const size_t row = (size_t)blockIdx.x * 4 + wid;
    const float4* xr = (const float4*)(x + row * C_DIM) + lane * 2;
    float4 a = xr[0], b = xr[1];
    float ss = a.x * a.x + a.y * a.y + a.z * a.z + a.w * a.w +
               b.x * b.x + b.y * b.y + b.z * b.z + b.w * b.w;
#pragma unroll
    for (int m = 1; m < 64; m <<= 1) ss += __shfl_xor(ss, m);
    float sc = 1.0f / fmaxf(sqrtf(ss), 1e-12f);
    union { unsigned short s[8]; int4 v; } o;
    o.s[0] = f2bf(a.x * sc); o.s[1] = f2bf(a.y * sc);
    o.s[2] = f2bf(a.z * sc); o.s[3] = f2bf(a.w * sc);
    o.s[4] = f2bf(b.x * sc); o.s[5] = f2bf(b.y * sc);
    o.s[6] = f2bf(b.z * sc); o.s[7] = f2bf(b.w * sc);
    *(int4*)(nf + row * C_DIM + lane * 8) = o.v;
}

// ---- sim keys = negkey(bf16(nf @ nf^T)) ----
// global_load_lds staging with T2 both-sides XOR swizzle (linear LDS dest,
// inverse-swizzled global source col-block, swizzled ds_read) -> 2 lanes/bank.
// symmetric==1: compute only tiles J>=I, write off-diag transposed via LDS bounce.
__global__ __launch_bounds__(256) void gemm_sim(const unsigned short* __restrict__ nf,
                                                unsigned short* __restrict__ simk,
                                                int rowBase, int symmetric) {
    __shared__ unsigned short smem[128 * 136];          // As[0:8192) Bs[8192:16384); Cs = whole
    unsigned short* As = smem;
    unsigned short* Bs = smem + 8192;
    const int tI = blockIdx.y, tJ = blockIdx.x;
    if (symmetric && tJ < tI) return;
    const int tid = threadIdx.x;
    const int wid = tid >> 6, lane = tid & 63;
    const int wm = wid >> 1, wn = wid & 1;
    const int gr = rowBase + tI * 128;
    const int gc = tJ * 128;
    f32x4 zero = {0.f, 0.f, 0.f, 0.f};
    f32x4 acc[4][4];
#pragma unroll
    for (int m = 0; m < 4; ++m)
#pragma unroll
        for (int n = 0; n < 4; ++n) acc[m][n] = zero;

    const int lr = lane >> 3, lcb = lane & 7;           // chunk-local row / col-block

    for (int k0 = 0; k0 < C_DIM; k0 += 64) {
#pragma unroll
        for (int i = 0; i < 4; ++i) {
            const int chunk = wid * 4 + i;              // wave-uniform
            const int r = chunk * 8 + lr;
            const int sc = (lcb ^ (r & 7)) << 3;        // inverse-swizzled source col
            gl_lds16(nf + (size_t)(gr + r) * C_DIM + k0 + sc, As + chunk * 512);
            gl_lds16(nf + (size_t)(gc + r) * C_DIM + k0 + sc, Bs + chunk * 512);
        }
        __syncthreads();
#pragma unroll
        for (int kk = 0; kk < 2; ++kk) {
            const int krow = kk * 32 + (lane >> 4) * 8;
            bf16x8 a[4], b[4];
#pragma unroll
            for (int m = 0; m < 4; ++m) {
                const int R = wm * 64 + m * 16 + (lane & 15);
                a[m] = *(const bf16x8*)&As[R * 64 + (krow ^ ((R & 7) << 3))];
            }
#pragma unroll
            for (int n = 0; n < 4; ++n) {
                const int R = wn * 64 + n * 16 + (lane & 15);
                b[n] = *(const bf16x8*)&Bs[R * 64 + (krow ^ ((R & 7) << 3))];
            }
#pragma unroll
            for (int m = 0; m < 4; ++m)
#pragma unroll
                for (int n = 0; n < 4; ++n)
                    acc[m][n] = __builtin_amdgcn_mfma_f32_16x16x32_bf16(a[m], b[n], acc[m][n], 0, 0, 0);
        }
        __syncthreads();
    }

    // direct write (rows gr+, cols gc+); C/D layout: col=lane&15, row=(lane>>4)*4+j
    const int lro = wm * 64 + ((lane >> 4) << 2);
    const int lco = wn * 64 + (lane & 15);
#pragma unroll
    for (int m = 0; m < 4; ++m)
#pragma unroll
        for (int n = 0; n < 4; ++n)
#pragma unroll
            for (int j = 0; j < 4; ++j)
                simk[(size_t)(gr - rowBase + lro + m * 16 + j) * B_N + gc + lco + n * 16] =
                    (unsigned short)negkey(f2bf(acc[m][n][j]));

    if (symmetric && tJ > tI) {
        // bounce keys through Cs[c][r] (c-major, stride 136) then store transposed tile
        unsigned short* Cs = smem;                       // aliases As/Bs (safe: post-barrier)
#pragma unroll
        for (int m = 0; m < 4; ++m)
#pragma unroll
            for (int n = 0; n < 4; ++n) {
                const int c = wn * 64 + n * 16 + (lane & 15);
                const int r0 = wm * 64 + m * 16 + ((lane >> 4) << 2);
                ushort4 pk;
                pk.x = (unsigned short)negkey(f2bf(acc[m][n][0]));
                pk.y = (unsigned short)negkey(f2bf(acc[m][n][1]));
                pk.z = (unsigned short)negkey(f2bf(acc[m][n][2]));
                pk.w = (unsigned short)negkey(f2bf(acc[m][n][3]));
                *(ushort4*)&Cs[c * 136 + r0] = pk;
            }
        __syncthreads();
#pragma unroll
        for (int s = 0; s < 8; ++s) {
            const int c = s * 16 + (tid >> 4);
            const int rb = (tid & 15) * 8;
            int4 v = *(const int4*)&Cs[c * 136 + rb];
            *(int4*)&simk[(size_t)(gc + c) * B_N + gr + rb] = v;
        }
    }
}

// digit select: per-lane bin counts a0..a3 of a 256-bin hist, suffix-scan, pick digit
__device__ __forceinline__ void digit_common(int a0, int a1, int a2, int a3, int lane,
                                             int krem, unsigned& dg, int& krem_out) {
    int ls3 = a3, ls2 = a2 + ls3, ls1 = a1 + ls2, ls0 = a0 + ls1;
    int s = ls0;
#pragma unroll
    for (int off = 1; off < 64; off <<= 1) {
        int t = __shfl_down(s, off);
        if (lane + off < 64) s += t;
    }
    const int E = s - ls0;                        // suffix sum over higher lanes
    unsigned long long m = __ballot((E + ls0) >= krem);
    int hi = m ? (63 - __clzll(m)) : 0;
    int k, kr;
    if ((E + ls3) >= krem)      { k = 3; kr = krem - E; }
    else if ((E + ls2) >= krem) { k = 2; kr = krem - (E + ls3); }
    else if ((E + ls1) >= krem) { k = 1; kr = krem - (E + ls2); }
    else                        { k = 0; kr = krem - (E + ls1); }
    dg = (unsigned)__shfl(lane * 4 + k, hi);
    krem_out = __shfl(kr, hi);
}
__device__ __forceinline__ void digit4(const int h[][256], int lane, int krem,
                                       unsigned& dg, int& krem_out) {
    int a0 = 0, a1 = 0, a2 = 0, a3 = 0;
#pragma unroll
    for (int w = 0; w < 4; ++w) {
        a0 += h[w][lane * 4 + 0]; a1 += h[w][lane * 4 + 1];
        a2 += h[w][lane * 4 + 2]; a3 += h[w][lane * 4 + 3];
    }
    digit_common(a0, a1, a2, a3, lane, krem, dg, krem_out);
}
__device__ __forceinline__ void digit1(const int* h, int lane, int krem,
                                       unsigned& dg, int& krem_out) {
    digit_common(h[lane * 4], h[lane * 4 + 1], h[lane * 4 + 2], h[lane * 4 + 3],
                 lane, krem, dg, krem_out);
}

// ---- block-per-row selection + loss (R6 structure, unchanged) ----
__global__ __launch_bounds__(256) void select_loss(const unsigned short* __restrict__ simk,
                                                   const unsigned char* __restrict__ tgb,
                                                   const unsigned char* __restrict__ cmb,
                                                   float* __restrict__ out, int rowBase) {
    __shared__ int hG[16 * 257];       // 4-lane-group hists
    __shared__ int hN2[4][256];        // per-wave low-byte hists (uniform spread)
    __shared__ int cN[256];            // compacted high-byte hist
    __shared__ int posk[512];          // same-class keys (class size ~82)
    __shared__ int nlist[64];          // strictly-selected negative keys (<=63)
    __shared__ int posn, nln;

    const int tid = threadIdx.x;
    const int wid = tid >> 6, lane = tid & 63;
    const int row = rowBase + blockIdx.x;
    const unsigned short* srow = simk + (size_t)blockIdx.x * B_N;
    const int ti = tgb[row];
    const unsigned char* mrow = cmb + (size_t)ti * 1024;
    int* hGg = &hG[((tid >> 2) & 15) * 257];

    int4 A[4];
    unsigned mpk = 0;
#pragma unroll
    for (int q = 0; q < 4; ++q) {
        A[q] = *(const int4*)(srow + q * 2048 + tid * 8);
        mpk |= ((unsigned)mrow[q * 256 + tid]) << (8 * q);
    }

    for (int i = tid; i < 16 * 257; i += 256) hG[i] = 0;
    int4 z4 = {0, 0, 0, 0};
    ((int4*)hN2)[tid] = z4;
    if (tid == 0) { posn = 0; nln = 0; }
    __syncthreads();                                             // B1

#define ELEM_LOOP(BODY)                                                          \
    _Pragma("unroll")                                                            \
    for (int q = 0; q < 4; ++q) {                                                \
        _Pragma("unroll")                                                        \
        for (int d = 0; d < 4; ++d) {                                            \
            unsigned w32 = (unsigned)(d == 0 ? A[q].x : d == 1 ? A[q].y          \
                                    : d == 2 ? A[q].z : A[q].w);                 \
            _Pragma("unroll")                                                    \
            for (int h2 = 0; h2 < 2; ++h2) {                                     \
                unsigned key = h2 ? (w32 >> 16) : (w32 & 0xFFFFu);               \
                bool same = (mpk >> (q * 8 + d * 2 + h2)) & 1u;                  \
                BODY                                                             \
            }                                                                    \
        }                                                                        \
    }

    // scan 1: negative high-byte group-hist; positives compact-collect
    ELEM_LOOP(
        if (!same) atomicAdd(&hGg[key >> 8], 1);
        else { int p = atomicAdd(&posn, 1); if (p < 512) posk[p] = (int)key; }
    )
    __syncthreads();                                             // B2

    {
        int s = 0;
#pragma unroll
        for (int g = 0; g < 16; ++g) s += hG[g * 257 + tid];
        cN[tid] = s;
    }
    __syncthreads();                                             // B3

    unsigned nhi; int krem;
    digit1(cN, lane, 64, nhi, krem);

    ELEM_LOOP(
        if (!same && (key >> 8) == nhi) atomicAdd(&hN2[wid][key & 0xFFu], 1);
    )
    __syncthreads();                                             // B4

    unsigned nlo; int nkrem;
    digit4(hN2, lane, krem, nlo, nkrem);
    const unsigned nprefix = (nhi << 8) | nlo;

    ELEM_LOOP(
        if (!same && key > nprefix) {
            int p = atomicAdd(&nln, 1);
            if (p < 64) nlist[p] = (int)key;
        }
    )
#undef ELEM_LOOP
    __syncthreads();                                             // B5

    if (wid == 0) {
        const int ncnt = nln < 64 ? nln : 64;
        float Sl = (lane < ncnt) ? __expf(2.0f * bf2f(unkey((unsigned)nlist[lane]))) : 0.f;
#pragma unroll
        for (int off = 1; off < 64; off <<= 1) Sl += __shfl_xor(Sl, off);

        const int np = posn < 512 ? posn : 512;
        unsigned k16[8];
#pragma unroll
        for (int r = 0; r < 8; ++r) {
            unsigned best = 0xFFFFFFFFu;
            for (int j = lane; j < np; j += 64) {
                unsigned cand = (((unsigned)posk[j]) << 16) | (unsigned)j;
                best = best < cand ? best : cand;
            }
#pragma unroll
            for (int off = 1; off < 64; off <<= 1) {
                unsigned o = (unsigned)__shfl_xor((int)best, off);
                best = best < o ? best : o;
            }
            k16[r] = best >> 16;                        // 0xFFFF => none left
            if (lane == 0 && k16[r] != 0xFFFFu)
                posk[best & 0xFFFFu] = 0xFFFF;          // consume (sentinel max)
        }
        if (lane == 0) {
            float S = Sl;
            if (nprefix != 0u) S += (float)nkrem * __expf(2.0f * bf2f(unkey(nprefix)));
            float acc = 0.f;
#pragma unroll
            for (int r = 0; r < 8; ++r) {
                if (k16[r] != 0xFFFFu) {                // <8 positives => zero contribution
                    float p = bf2f(unkey(k16[r]));
                    acc += logf(__expf(2.0f * p) + S) - 2.0f * p;
                }
            }
            out[row] = acc * 0.125f;
        }
    }
}

extern "C" void kernel_launch(void* const* d_in, const int* in_sizes, int n_in,
                              void* d_out, int out_size, void* d_ws, size_t ws_size,
                              hipStream_t stream) {
    const float* newf = (const float*)d_in[1];
    const unsigned int* tgtw = (const unsigned int*)d_in[2];
    float* out = (float*)d_out;
    char* ws = (char*)d_ws;
    unsigned char* tgb = (unsigned char*)ws;                         // 8 KB
    unsigned long long* cm = (unsigned long long*)(ws + 8192);       // 100 KB
    unsigned short* nf = (unsigned short*)(ws + 110592);             // 8 MB
    unsigned short* simk = (unsigned short*)(ws + 110592 + (size_t)B_N * C_DIM * 2);

    size_t fixed = 110592 + (size_t)B_N * C_DIM * 2;
    size_t avail = (ws_size > fixed) ? (ws_size - fixed) : 0;
    long maxRows = (long)(avail / ((size_t)B_N * 2));
    int chunk = (int)((maxRows / 128) * 128);
    if (chunk < 128) chunk = 128;
    if (chunk > B_N) chunk = B_N;

    hipLaunchKernelGGL(prep_tgt, dim3(1), dim3(256), 0, stream, tgtw, tgb);
    hipLaunchKernelGGL(class_masks, dim3(100), dim3(128), 0, stream, tgb, cm);
    hipLaunchKernelGGL(normalize_k, dim3(B_N / 4), dim3(256), 0, stream, newf, nf);
    if (chunk == B_N) {
        // full matrix fits: symmetric GEMM (tiles J>=I only, transposed writes)
        hipLaunchKernelGGL(gemm_sim, dim3(NT, NT), dim3(256), 0, stream, nf, simk, 0, 1);
        hipLaunchKernelGGL(select_loss, dim3(B_N), dim3(256), 0, stream,
                           simk, tgb, (const unsigned char*)cm, out, 0);
    } else {
        for (int r0 = 0; r0 < B_N; r0 += chunk) {
            int rows = (B_N - r0 < chunk) ? (B_N - r0) : chunk;
            hipLaunchKernelGGL(gemm_sim, dim3(NT, rows / 128), dim3(256), 0, stream,
                               nf, simk, r0, 0);
            hipLaunchKernelGGL(select_loss, dim3(rows), dim3(256), 0, stream,
                               simk, tgb, (const unsigned char*)cm, out, r0);
        }
    }
}